// Round 4
// baseline (640.703 us; speedup 1.0000x reference)
//
#include <hip/hip_runtime.h>
#include <math.h>

// ---------------------------------------------------------------------------
// JKNet: 2-layer GCN (sym-norm A+I) + sum-JK + linear + log_softmax.
// Round 10: keep XCD-pinned feature-split gather (r9 win: 179 -> ~110us/layer).
// Fix r9's two regressions: (1) head_k rebuilt -- lw staged in LDS, persistent
// grid-stride blocks, ILP-4 accumulators (was: serial 128-FMA chain + global
// lw loads per iter = 120us). (2) permute/gemm1 un-merged -- the union forced
// permute blocks to inherit gemm's 34KB LDS -> 19.5% occupancy.
// ---------------------------------------------------------------------------

#define NPAD (1 << 17)   // padded node-array stride (N=100000)
#define CHUNK 1024       // scan chunk (elements per block)

typedef __attribute__((ext_vector_type(8))) short short8;
typedef __attribute__((ext_vector_type(4))) float f32x4;

__device__ inline unsigned short f2bf(float f) {
    unsigned u = __builtin_bit_cast(unsigned, f);
    return (unsigned short)((u + 0x7fffu + ((u >> 16) & 1u)) >> 16);
}
__device__ inline float bflo(unsigned u) { return __builtin_bit_cast(float, u << 16); }
__device__ inline float bfhi(unsigned u) { return __builtin_bit_cast(float, u & 0xffff0000u); }

// ---- CSR build ------------------------------------------------------------

// Union dispatch: hist (blocks < histB) + weight cast/transpose (rest).
// Both parts are low-resource (no LDS, few VGPRs) so the union is safe.
__global__ void mega1(const int* __restrict__ dst, int* __restrict__ cnt, int E, int histB,
                      const float* __restrict__ W1, unsigned short* __restrict__ Wt1,
                      const float* __restrict__ W2, unsigned short* __restrict__ Wt2) {
    int b = blockIdx.x;
    if (b < histB) {
        int e = b * 256 + threadIdx.x;
        if (e < E) atomicAdd(&cnt[dst[e]], 1);
    } else {
        int i = (b - histB) * 256 + threadIdx.x;
        if (i < 256 * 128) {
            int k = i >> 7, nn = i & 127;
            Wt1[nn * 256 + k] = f2bf(W1[i]);
        } else {
            int j = i - 256 * 128;
            if (j < 128 * 128) {
                int k = j >> 7, nn = j & 127;
                Wt2[nn * 128 + k] = f2bf(W2[j]);
            }
        }
    }
}

__global__ void scan_partial(const int* __restrict__ cnt, int* __restrict__ partial, int n) {
    __shared__ int sdata[4];
    int b = blockIdx.x, t = threadIdx.x;
    int base = b * CHUNK;
    int sum = 0;
    for (int i = t; i < CHUNK; i += 256) {
        int idx = base + i;
        if (idx < n) sum += cnt[idx];
    }
#pragma unroll
    for (int off = 32; off > 0; off >>= 1) sum += __shfl_down(sum, off, 64);
    if ((t & 63) == 0) sdata[t >> 6] = sum;
    __syncthreads();
    if (t == 0) partial[b] = sdata[0] + sdata[1] + sdata[2] + sdata[3];
}

// parallel exclusive scan over nblk (<=128) block sums; 1 block x 128 threads
__global__ void scan_small(int* partial, int nblk) {
    __shared__ int sm[128];
    int t = threadIdx.x;
    int v = (t < nblk) ? partial[t] : 0;
    int x = v;
    sm[t] = x;
    __syncthreads();
    for (int off = 1; off < 128; off <<= 1) {
        int y = (t >= off) ? sm[t - off] : 0;
        __syncthreads();
        x += y;
        sm[t] = x;
        __syncthreads();
    }
    if (t < nblk) partial[t] = x - v;   // exclusive
}

__global__ void scan_final(const int* __restrict__ cnt, const int* __restrict__ partial,
                           int* __restrict__ offs, int* __restrict__ cursor,
                           float* __restrict__ dis, int n) {
    __shared__ int wsum[4];
    int b = blockIdx.x, t = threadIdx.x;
    int lane = t & 63, w = t >> 6;
    int base = b * CHUNK + t * 4;
    int v[4];
#pragma unroll
    for (int j = 0; j < 4; j++) v[j] = (base + j < n) ? cnt[base + j] : 0;
    int s4 = v[0] + v[1] + v[2] + v[3];
    int inc = s4;
#pragma unroll
    for (int off = 1; off < 64; off <<= 1) {
        int x = __shfl_up(inc, off, 64);
        if (lane >= off) inc += x;
    }
    if (lane == 63) wsum[w] = inc;
    __syncthreads();
    int woff = 0;
    for (int i = 0; i < 4; i++) if (i < w) woff += wsum[i];
    int pos = partial[b] + woff + (inc - s4);
#pragma unroll
    for (int j = 0; j < 4; j++) {
        int idx = base + j;
        if (idx < n) {
            offs[idx] = pos;
            cursor[idx] = pos;
            dis[idx] = rsqrtf((float)(v[j] + 1));  // deg = incoming + self-loop
            pos += v[j];
        }
    }
}

// Single-pass permute: standalone (28 VGPR, no LDS -> full occupancy).
__global__ void permute_all(const int* __restrict__ src, const int* __restrict__ dst,
                            const float* __restrict__ dis,
                            int* __restrict__ cursor, int2* __restrict__ eadj, int E) {
    int e = blockIdx.x * 256 + threadIdx.x;
    if (e < E) {
        int d = dst[e];
        int s = src[e];
        int pos = atomicAdd(&cursor[d], 1);
        eadj[pos] = make_int2(s, __float_as_int(dis[s] * dis[d]));
    }
}

// ---- MFMA GEMM body: Hb[n,128](bf16) = A[n,K] @ W[K,128] ------------------
template<bool ABF16>
__device__ void gemm_body(int bid, const void* __restrict__ Ap,
                          const unsigned short* __restrict__ Wt,
                          unsigned short* __restrict__ Hb,
                          int n, int K, unsigned short* bs) {
    const int tid = threadIdx.x;
    const int wave = tid >> 6, lane = tid & 63;
    const int quad = lane >> 4, mrow = lane & 15;
    const int arow_g = bid * 64 + wave * 16 + mrow;
    const int arow = arow_g < n ? arow_g : n - 1;

    f32x4 acc[8];
#pragma unroll
    for (int t = 0; t < 8; t++) acc[t] = (f32x4){0.f, 0.f, 0.f, 0.f};

    const float* Af = (const float*)Ap;
    const unsigned short* Ab = (const unsigned short*)Ap;

    for (int kc = 0; kc < K; kc += 128) {
        __syncthreads();
        for (int i = tid; i < 2048; i += 256) {
            int row = i >> 4, c8 = i & 15;
            *(short8*)&bs[row * 136 + c8 * 8] = *(const short8*)&Wt[row * K + kc + c8 * 8];
        }
        __syncthreads();
#pragma unroll
        for (int kt = 0; kt < 128; kt += 32) {
            union { short8 v; unsigned short u[8]; } A;
            if (ABF16) {
                A.v = *(const short8*)&Ab[(size_t)arow * K + kc + kt + quad * 8];
            } else {
                const float* ap = &Af[(size_t)arow * K + kc + kt + quad * 8];
                float4 p0 = *(const float4*)ap;
                float4 p1 = *(const float4*)(ap + 4);
                A.u[0] = f2bf(p0.x); A.u[1] = f2bf(p0.y);
                A.u[2] = f2bf(p0.z); A.u[3] = f2bf(p0.w);
                A.u[4] = f2bf(p1.x); A.u[5] = f2bf(p1.y);
                A.u[6] = f2bf(p1.z); A.u[7] = f2bf(p1.w);
            }
#pragma unroll
            for (int nt = 0; nt < 8; nt++) {
                short8 B = *(const short8*)&bs[(nt * 16 + mrow) * 136 + kt + quad * 8];
                acc[nt] = __builtin_amdgcn_mfma_f32_16x16x32_bf16(A.v, B, acc[nt], 0, 0, 0);
            }
        }
    }
    const int drow0 = bid * 64 + wave * 16 + quad * 4;
#pragma unroll
    for (int r = 0; r < 4; r++) {
        int dr = drow0 + r;
        if (dr < n) {
#pragma unroll
            for (int nt = 0; nt < 8; nt++)
                Hb[(size_t)dr * 128 + nt * 16 + mrow] = f2bf(acc[nt][r]);
        }
    }
}

__global__ __launch_bounds__(256) void gemm1_k(const float* __restrict__ x,
                                               const unsigned short* __restrict__ Wt1,
                                               unsigned short* __restrict__ Hb, int n) {
    __shared__ unsigned short bs[128 * 136];
    gemm_body<false>(blockIdx.x, x, Wt1, Hb, n, 256, bs);
}

__global__ __launch_bounds__(256) void gemm2_k(const unsigned short* __restrict__ X1b,
                                               const unsigned short* __restrict__ Wt2,
                                               unsigned short* __restrict__ Hb, int n) {
    __shared__ unsigned short bs[128 * 136];
    gemm_body<true>(blockIdx.x, X1b, Wt2, Hb, n, 128, bs);
}

// ---- CSR gather, half-feature, XCD-pinned ---------------------------------
// Block decode: xcd = bid%8 (native round-robin); half = xcd>>2 selects
// features [half*64, half*64+64); nb = (bid>>3)*4 + (xcd&3) is the node-block.
// Wave = 1 node. lane = grp*8 + fl: 8 edge-groups x 8 feature-lanes; a group's
// 8 lanes read one 128B half-row (exactly one cache line). Pipeline depth-2,
// 16 edges per stage.
__global__ __launch_bounds__(256) void gather_h(const unsigned short* __restrict__ Hb,
                                                const int2* __restrict__ eadj,
                                                const int* __restrict__ offs,
                                                const int* __restrict__ cnt,
                                                const float* __restrict__ dis,
                                                const float* __restrict__ bias,
                                                unsigned short* __restrict__ outb,
                                                int n) {
    const int b = blockIdx.x;
    const int xcd = b & 7;
    const int half = xcd >> 2;
    const int nb = ((b >> 3) << 2) | (xcd & 3);
    const int w = threadIdx.x >> 6, lane = threadIdx.x & 63;
    const int grp = lane >> 3, fl = lane & 7;
    const int node = nb * 4 + w;
    const int nd = node < n ? node : n - 1;
    const int st = offs[nd], c = cnt[nd];
    const unsigned short* Hfl = Hb + half * 64 + fl * 8;

    float acc[8];
#pragma unroll
    for (int k = 0; k < 8; k++) acc[k] = 0.f;

    const int2* ep = eadj + st;
    for (int kk = 0; kk < c; kk += 64) {
        int li = kk + lane;
        int2 me = ep[li < c ? li : c - 1];             // c>0 guaranteed in loop
        float mw = li < c ? __int_as_float(me.y) : 0.f;
        int cend = (c - kk) < 64 ? (c - kk) : 64;

        // prologue: edges grp / 8+grp
        int   s0 = __shfl(me.x, grp, 64);
        float w0 = __shfl(mw,  grp, 64);
        int   s1 = __shfl(me.x, 8 + grp, 64);
        float w1 = __shfl(mw,  8 + grp, 64);
        uint4 r0 = *(const uint4*)(Hfl + (size_t)s0 * 128);
        uint4 r1 = *(const uint4*)(Hfl + (size_t)s1 * 128);

        for (int j = 0; j < cend; j += 16) {
            int jn = (j + 16 < cend) ? j + 16 : j;     // wave-uniform select
            int   sn0 = __shfl(me.x, jn + grp, 64);
            float wn0 = __shfl(mw,  jn + grp, 64);
            int   sn1 = __shfl(me.x, jn + 8 + grp, 64);
            float wn1 = __shfl(mw,  jn + 8 + grp, 64);
            uint4 rn0 = *(const uint4*)(Hfl + (size_t)sn0 * 128);  // issued before
            uint4 rn1 = *(const uint4*)(Hfl + (size_t)sn1 * 128);  // consuming r0/r1
            acc[0] = fmaf(bflo(r0.x), w0, acc[0]); acc[1] = fmaf(bfhi(r0.x), w0, acc[1]);
            acc[2] = fmaf(bflo(r0.y), w0, acc[2]); acc[3] = fmaf(bfhi(r0.y), w0, acc[3]);
            acc[4] = fmaf(bflo(r0.z), w0, acc[4]); acc[5] = fmaf(bfhi(r0.z), w0, acc[5]);
            acc[6] = fmaf(bflo(r0.w), w0, acc[6]); acc[7] = fmaf(bfhi(r0.w), w0, acc[7]);
            acc[0] = fmaf(bflo(r1.x), w1, acc[0]); acc[1] = fmaf(bfhi(r1.x), w1, acc[1]);
            acc[2] = fmaf(bflo(r1.y), w1, acc[2]); acc[3] = fmaf(bfhi(r1.y), w1, acc[3]);
            acc[4] = fmaf(bflo(r1.z), w1, acc[4]); acc[5] = fmaf(bfhi(r1.z), w1, acc[5]);
            acc[6] = fmaf(bflo(r1.w), w1, acc[6]); acc[7] = fmaf(bfhi(r1.w), w1, acc[7]);
            r0 = rn0; r1 = rn1; w0 = wn0; w1 = wn1;
        }
    }
    // reduce across the 8 edge-groups
#pragma unroll
    for (int k = 0; k < 8; k++) {
        acc[k] += __shfl_xor(acc[k], 8, 64);
        acc[k] += __shfl_xor(acc[k], 16, 64);
        acc[k] += __shfl_xor(acc[k], 32, 64);
    }
    // self-loop + bias + relu (8 contiguous features per fl-lane, this half)
    float dd = dis[nd], sn = dd * dd;
    uint4 rs = *(const uint4*)(Hfl + (size_t)nd * 128);
    float4 bb0 = ((const float4*)bias)[half * 16 + fl * 2];
    float4 bb1 = ((const float4*)bias)[half * 16 + fl * 2 + 1];
    acc[0] = fmaf(bflo(rs.x), sn, acc[0]) + bb0.x;
    acc[1] = fmaf(bfhi(rs.x), sn, acc[1]) + bb0.y;
    acc[2] = fmaf(bflo(rs.y), sn, acc[2]) + bb0.z;
    acc[3] = fmaf(bfhi(rs.y), sn, acc[3]) + bb0.w;
    acc[4] = fmaf(bflo(rs.z), sn, acc[4]) + bb1.x;
    acc[5] = fmaf(bfhi(rs.z), sn, acc[5]) + bb1.y;
    acc[6] = fmaf(bflo(rs.w), sn, acc[6]) + bb1.z;
    acc[7] = fmaf(bfhi(rs.w), sn, acc[7]) + bb1.w;
#pragma unroll
    for (int k = 0; k < 8; k++) acc[k] = acc[k] > 0.f ? acc[k] : 0.f;

    if (node < n && grp == 0) {
        uint4 pk;
        pk.x = ((unsigned)f2bf(acc[1]) << 16) | (unsigned)f2bf(acc[0]);
        pk.y = ((unsigned)f2bf(acc[3]) << 16) | (unsigned)f2bf(acc[2]);
        pk.z = ((unsigned)f2bf(acc[5]) << 16) | (unsigned)f2bf(acc[4]);
        pk.w = ((unsigned)f2bf(acc[7]) << 16) | (unsigned)f2bf(acc[6]);
        *(uint4*)(outb + (size_t)node * 128 + half * 64 + fl * 8) = pk;
    }
}

// ---- JK head: out = log_softmax((x1+x2) @ lw + lb) ------------------------
// Persistent grid-stride blocks; lw staged once per block in LDS (21KB,
// lane-stride-1 -> conflict-free); ILP-4 accumulators break the serial
// FMA chain that made the r9 version issue-starved (VALUBusy 42%).
__global__ __launch_bounds__(256) void head_k(const unsigned short* __restrict__ x1b,
                                              const unsigned short* __restrict__ x2b,
                                              const float* __restrict__ lw,
                                              const float* __restrict__ lb,
                                              float* __restrict__ out, int n, int nblk) {
    __shared__ float lws[128 * 41];
    __shared__ float s[4][128];
    const int tid = threadIdx.x;
    const int w = tid >> 6, lane = tid & 63;
    for (int i = tid; i < 128 * 41; i += 256) lws[i] = lw[i];
    __syncthreads();
    const float lbv = (lane < 41) ? lb[lane] : 0.f;

    for (int blk = blockIdx.x; blk * 4 < n; blk += nblk) {
        const int node = blk * 4 + w;
        const int nd = node < n ? node : n - 1;
        unsigned u1 = *(const unsigned*)(x1b + (size_t)nd * 128 + lane * 2);
        unsigned u2 = *(const unsigned*)(x2b + (size_t)nd * 128 + lane * 2);
        s[w][lane * 2]     = bflo(u1) + bflo(u2);
        s[w][lane * 2 + 1] = bfhi(u1) + bfhi(u2);
        // same-wave LDS write->read; compiler inserts the lgkmcnt wait
        const bool act = (node < n) && (lane < 41);
        float v0 = 0.f, v1 = 0.f, v2 = 0.f, v3 = 0.f;
        if (act) {
#pragma unroll 8
            for (int f = 0; f < 32; f++) {
                v0 = fmaf(s[w][f],      lws[f * 41 + lane],        v0);
                v1 = fmaf(s[w][f + 32], lws[(f + 32) * 41 + lane], v1);
                v2 = fmaf(s[w][f + 64], lws[(f + 64) * 41 + lane], v2);
                v3 = fmaf(s[w][f + 96], lws[(f + 96) * 41 + lane], v3);
            }
        }
        float val = (v0 + v1) + (v2 + v3) + lbv;
        float m = act ? val : -INFINITY;
#pragma unroll
        for (int off = 32; off > 0; off >>= 1) m = fmaxf(m, __shfl_xor(m, off, 64));
        float e = act ? expf(val - m) : 0.f;
#pragma unroll
        for (int off = 32; off > 0; off >>= 1) e += __shfl_xor(e, off, 64);
        if (act) out[(size_t)node * 41 + lane] = val - m - logf(e);
    }
}

extern "C" void kernel_launch(void* const* d_in, const int* in_sizes, int n_in,
                              void* d_out, int out_size, void* d_ws, size_t ws_size,
                              hipStream_t stream) {
    const float* x  = (const float*)d_in[0];
    const int*   ei = (const int*)d_in[1];
    const float* W1 = (const float*)d_in[2];
    const float* b1 = (const float*)d_in[3];
    const float* W2 = (const float*)d_in[4];
    const float* b2 = (const float*)d_in[5];
    const float* lw = (const float*)d_in[6];
    const float* lb = (const float*)d_in[7];
    float* out = (float*)d_out;

    const int n = in_sizes[0] / 256;   // 100000
    const int E = in_sizes[1] / 2;     // 1600000
    const int* src = ei;
    const int* dst = ei + E;

    // workspace layout (~92 MB)
    int*   cnt     = (int*)d_ws;                       // NPAD
    int*   offs    = cnt + NPAD;                       // NPAD
    int*   cursor  = offs + NPAD;                      // NPAD
    int*   partial = cursor + NPAD;                    // 1024
    float* dis     = (float*)(partial + 1024);         // NPAD
    size_t Epad    = ((size_t)E + 255) & ~(size_t)255;
    int2*  eadj    = (int2*)(dis + NPAD);              // Epad pairs (8 B)
    unsigned short* Wt1 = (unsigned short*)(eadj + Epad);  // 256*128 bf16
    unsigned short* Wt2 = Wt1 + 256 * 128;                 // 128*128 bf16
    unsigned short* Hb  = Wt2 + 128 * 128;                 // n*128 bf16
    unsigned short* X1b = Hb + (size_t)n * 128;            // n*128 bf16
    unsigned short* X2b = X1b + (size_t)n * 128;           // n*128 bf16

    const int nscan = (n + CHUNK - 1) / CHUNK;
    const int histB = (E + 255) / 256;                 // 6250
    const int wcastB = (256 * 128 + 128 * 128 + 255) / 256;  // 192
    const int gemmB = (n + 63) / 64;                   // 1563
    const int NB = (n + 3) / 4;                        // node-blocks (4/block)
    const int gathB = 8 * ((NB + 3) / 4);              // 8 XCD-combos
    const int headB = 1536;                            // persistent (6/CU LDS cap)

    hipMemsetAsync(cnt, 0, (size_t)n * sizeof(int), stream);

    // CSR hist + weight cast (independent, one low-resource dispatch)
    mega1<<<histB + wcastB, 256, 0, stream>>>(dst, cnt, E, histB, W1, Wt1, W2, Wt2);
    scan_partial<<<nscan, 256, 0, stream>>>(cnt, partial, n);
    scan_small<<<1, 128, 0, stream>>>(partial, nscan);
    scan_final<<<nscan, 256, 0, stream>>>(cnt, partial, offs, cursor, dis, n);
    permute_all<<<histB, 256, 0, stream>>>(src, dst, dis, cursor, eadj, E);

    // layer 1: transform + aggregate (feature-split, XCD-pinned)
    gemm1_k<<<gemmB, 256, 0, stream>>>(x, Wt1, Hb, n);
    gather_h<<<gathB, 256, 0, stream>>>(Hb, eadj, offs, cnt, dis, b1, X1b, n);

    // layer 2 transform + aggregate
    gemm2_k<<<gemmB, 256, 0, stream>>>(X1b, Wt2, Hb, n);
    gather_h<<<gathB, 256, 0, stream>>>(Hb, eadj, offs, cnt, dis, b2, X2b, n);

    // JK + linear + log_softmax
    head_k<<<headB, 256, 0, stream>>>(X1b, X2b, lw, lb, out, n, headB);
}

// Round 5
// 552.065 us; speedup vs baseline: 1.1606x; 1.1606x over previous
//
#include <hip/hip_runtime.h>
#include <math.h>

// ---------------------------------------------------------------------------
// JKNet: 2-layer GCN (sym-norm A+I) + sum-JK + linear + log_softmax.
// Round 11: MFMA head. The JK head is a [N,128]x[128,41] GEMM (1.05 GFLOP)
// that the per-lane VALU version executed in 128us (2 LDS reads/FMA, 41/64
// lanes). Rebuilt with mfma_f32_16x16x32_bf16 + bf16x2 error-compensated
// split (A,B each hi+lo; hi*hi+hi*lo+lo*hi => ~2^-16 rel error, below the
// pipeline's existing bf16 noise). Predicted ~20us. Everything else frozen
// from r10 (XCD-pinned feature-split gather, standalone permute, MFMA gemms).
// ---------------------------------------------------------------------------

#define NPAD (1 << 17)   // padded node-array stride (N=100000)
#define CHUNK 1024       // scan chunk (elements per block)

typedef __attribute__((ext_vector_type(8))) short short8;
typedef __attribute__((ext_vector_type(4))) float f32x4;

__device__ inline unsigned short f2bf(float f) {
    unsigned u = __builtin_bit_cast(unsigned, f);
    return (unsigned short)((u + 0x7fffu + ((u >> 16) & 1u)) >> 16);
}
__device__ inline float bf2f(unsigned short h) {
    return __builtin_bit_cast(float, (unsigned)h << 16);
}
__device__ inline float bflo(unsigned u) { return __builtin_bit_cast(float, u << 16); }
__device__ inline float bfhi(unsigned u) { return __builtin_bit_cast(float, u & 0xffff0000u); }

// ---- CSR build + weight prep ----------------------------------------------

// Union dispatch: hist | W1/W2 cast-transpose | lw split-transpose.
// All parts low-resource (no LDS, few VGPRs) -> union is safe.
__global__ void mega1(const int* __restrict__ dst, int* __restrict__ cnt, int E, int histB,
                      const float* __restrict__ W1, unsigned short* __restrict__ Wt1,
                      const float* __restrict__ W2, unsigned short* __restrict__ Wt2,
                      const float* __restrict__ lw, unsigned short* __restrict__ lwt_hi,
                      unsigned short* __restrict__ lwt_lo) {
    int b = blockIdx.x;
    if (b < histB) {
        int e = b * 256 + threadIdx.x;
        if (e < E) atomicAdd(&cnt[dst[e]], 1);
    } else {
        int i = (b - histB) * 256 + threadIdx.x;
        if (i < 256 * 128) {
            int k = i >> 7, nn = i & 127;
            Wt1[nn * 256 + k] = f2bf(W1[i]);
        } else if (i < 256 * 128 + 128 * 128) {
            int j = i - 256 * 128;
            int k = j >> 7, nn = j & 127;
            Wt2[nn * 128 + k] = f2bf(W2[j]);
        } else {
            int j = i - (256 * 128 + 128 * 128);
            if (j < 48 * 128) {
                int c = j >> 7, k = j & 127;       // lwt[c][k] = lw[k][c], pad c>=41
                float wv = (c < 41) ? lw[k * 41 + c] : 0.f;
                unsigned short hi = f2bf(wv);
                lwt_hi[c * 128 + k] = hi;
                lwt_lo[c * 128 + k] = f2bf(wv - bf2f(hi));
            }
        }
    }
}

__global__ void scan_partial(const int* __restrict__ cnt, int* __restrict__ partial, int n) {
    __shared__ int sdata[4];
    int b = blockIdx.x, t = threadIdx.x;
    int base = b * CHUNK;
    int sum = 0;
    for (int i = t; i < CHUNK; i += 256) {
        int idx = base + i;
        if (idx < n) sum += cnt[idx];
    }
#pragma unroll
    for (int off = 32; off > 0; off >>= 1) sum += __shfl_down(sum, off, 64);
    if ((t & 63) == 0) sdata[t >> 6] = sum;
    __syncthreads();
    if (t == 0) partial[b] = sdata[0] + sdata[1] + sdata[2] + sdata[3];
}

// parallel exclusive scan over nblk (<=128) block sums; 1 block x 128 threads
__global__ void scan_small(int* partial, int nblk) {
    __shared__ int sm[128];
    int t = threadIdx.x;
    int v = (t < nblk) ? partial[t] : 0;
    int x = v;
    sm[t] = x;
    __syncthreads();
    for (int off = 1; off < 128; off <<= 1) {
        int y = (t >= off) ? sm[t - off] : 0;
        __syncthreads();
        x += y;
        sm[t] = x;
        __syncthreads();
    }
    if (t < nblk) partial[t] = x - v;   // exclusive
}

__global__ void scan_final(const int* __restrict__ cnt, const int* __restrict__ partial,
                           int* __restrict__ offs, int* __restrict__ cursor,
                           float* __restrict__ dis, int n) {
    __shared__ int wsum[4];
    int b = blockIdx.x, t = threadIdx.x;
    int lane = t & 63, w = t >> 6;
    int base = b * CHUNK + t * 4;
    int v[4];
#pragma unroll
    for (int j = 0; j < 4; j++) v[j] = (base + j < n) ? cnt[base + j] : 0;
    int s4 = v[0] + v[1] + v[2] + v[3];
    int inc = s4;
#pragma unroll
    for (int off = 1; off < 64; off <<= 1) {
        int x = __shfl_up(inc, off, 64);
        if (lane >= off) inc += x;
    }
    if (lane == 63) wsum[w] = inc;
    __syncthreads();
    int woff = 0;
    for (int i = 0; i < 4; i++) if (i < w) woff += wsum[i];
    int pos = partial[b] + woff + (inc - s4);
#pragma unroll
    for (int j = 0; j < 4; j++) {
        int idx = base + j;
        if (idx < n) {
            offs[idx] = pos;
            cursor[idx] = pos;
            dis[idx] = rsqrtf((float)(v[j] + 1));  // deg = incoming + self-loop
            pos += v[j];
        }
    }
}

// Single-pass permute: standalone (28 VGPR, no LDS -> full occupancy).
__global__ void permute_all(const int* __restrict__ src, const int* __restrict__ dst,
                            const float* __restrict__ dis,
                            int* __restrict__ cursor, int2* __restrict__ eadj, int E) {
    int e = blockIdx.x * 256 + threadIdx.x;
    if (e < E) {
        int d = dst[e];
        int s = src[e];
        int pos = atomicAdd(&cursor[d], 1);
        eadj[pos] = make_int2(s, __float_as_int(dis[s] * dis[d]));
    }
}

// ---- MFMA GEMM body: Hb[n,128](bf16) = A[n,K] @ W[K,128] ------------------
template<bool ABF16>
__device__ void gemm_body(int bid, const void* __restrict__ Ap,
                          const unsigned short* __restrict__ Wt,
                          unsigned short* __restrict__ Hb,
                          int n, int K, unsigned short* bs) {
    const int tid = threadIdx.x;
    const int wave = tid >> 6, lane = tid & 63;
    const int quad = lane >> 4, mrow = lane & 15;
    const int arow_g = bid * 64 + wave * 16 + mrow;
    const int arow = arow_g < n ? arow_g : n - 1;

    f32x4 acc[8];
#pragma unroll
    for (int t = 0; t < 8; t++) acc[t] = (f32x4){0.f, 0.f, 0.f, 0.f};

    const float* Af = (const float*)Ap;
    const unsigned short* Ab = (const unsigned short*)Ap;

    for (int kc = 0; kc < K; kc += 128) {
        __syncthreads();
        for (int i = tid; i < 2048; i += 256) {
            int row = i >> 4, c8 = i & 15;
            *(short8*)&bs[row * 136 + c8 * 8] = *(const short8*)&Wt[row * K + kc + c8 * 8];
        }
        __syncthreads();
#pragma unroll
        for (int kt = 0; kt < 128; kt += 32) {
            union { short8 v; unsigned short u[8]; } A;
            if (ABF16) {
                A.v = *(const short8*)&Ab[(size_t)arow * K + kc + kt + quad * 8];
            } else {
                const float* ap = &Af[(size_t)arow * K + kc + kt + quad * 8];
                float4 p0 = *(const float4*)ap;
                float4 p1 = *(const float4*)(ap + 4);
                A.u[0] = f2bf(p0.x); A.u[1] = f2bf(p0.y);
                A.u[2] = f2bf(p0.z); A.u[3] = f2bf(p0.w);
                A.u[4] = f2bf(p1.x); A.u[5] = f2bf(p1.y);
                A.u[6] = f2bf(p1.z); A.u[7] = f2bf(p1.w);
            }
#pragma unroll
            for (int nt = 0; nt < 8; nt++) {
                short8 B = *(const short8*)&bs[(nt * 16 + mrow) * 136 + kt + quad * 8];
                acc[nt] = __builtin_amdgcn_mfma_f32_16x16x32_bf16(A.v, B, acc[nt], 0, 0, 0);
            }
        }
    }
    const int drow0 = bid * 64 + wave * 16 + quad * 4;
#pragma unroll
    for (int r = 0; r < 4; r++) {
        int dr = drow0 + r;
        if (dr < n) {
#pragma unroll
            for (int nt = 0; nt < 8; nt++)
                Hb[(size_t)dr * 128 + nt * 16 + mrow] = f2bf(acc[nt][r]);
        }
    }
}

__global__ __launch_bounds__(256) void gemm1_k(const float* __restrict__ x,
                                               const unsigned short* __restrict__ Wt1,
                                               unsigned short* __restrict__ Hb, int n) {
    __shared__ unsigned short bs[128 * 136];
    gemm_body<false>(blockIdx.x, x, Wt1, Hb, n, 256, bs);
}

__global__ __launch_bounds__(256) void gemm2_k(const unsigned short* __restrict__ X1b,
                                               const unsigned short* __restrict__ Wt2,
                                               unsigned short* __restrict__ Hb, int n) {
    __shared__ unsigned short bs[128 * 136];
    gemm_body<true>(blockIdx.x, X1b, Wt2, Hb, n, 128, bs);
}

// ---- CSR gather, half-feature, XCD-pinned ---------------------------------
// Block decode: xcd = bid%8 (native round-robin); half = xcd>>2 selects
// features [half*64, half*64+64); nb = (bid>>3)*4 + (xcd&3) is the node-block.
// Wave = 1 node. lane = grp*8 + fl: 8 edge-groups x 8 feature-lanes; a group's
// 8 lanes read one 128B half-row (exactly one cache line). Pipeline depth-2,
// 16 edges per stage.
__global__ __launch_bounds__(256) void gather_h(const unsigned short* __restrict__ Hb,
                                                const int2* __restrict__ eadj,
                                                const int* __restrict__ offs,
                                                const int* __restrict__ cnt,
                                                const float* __restrict__ dis,
                                                const float* __restrict__ bias,
                                                unsigned short* __restrict__ outb,
                                                int n) {
    const int b = blockIdx.x;
    const int xcd = b & 7;
    const int half = xcd >> 2;
    const int nb = ((b >> 3) << 2) | (xcd & 3);
    const int w = threadIdx.x >> 6, lane = threadIdx.x & 63;
    const int grp = lane >> 3, fl = lane & 7;
    const int node = nb * 4 + w;
    const int nd = node < n ? node : n - 1;
    const int st = offs[nd], c = cnt[nd];
    const unsigned short* Hfl = Hb + half * 64 + fl * 8;

    float acc[8];
#pragma unroll
    for (int k = 0; k < 8; k++) acc[k] = 0.f;

    const int2* ep = eadj + st;
    for (int kk = 0; kk < c; kk += 64) {
        int li = kk + lane;
        int2 me = ep[li < c ? li : c - 1];             // c>0 guaranteed in loop
        float mw = li < c ? __int_as_float(me.y) : 0.f;
        int cend = (c - kk) < 64 ? (c - kk) : 64;

        // prologue: edges grp / 8+grp
        int   s0 = __shfl(me.x, grp, 64);
        float w0 = __shfl(mw,  grp, 64);
        int   s1 = __shfl(me.x, 8 + grp, 64);
        float w1 = __shfl(mw,  8 + grp, 64);
        uint4 r0 = *(const uint4*)(Hfl + (size_t)s0 * 128);
        uint4 r1 = *(const uint4*)(Hfl + (size_t)s1 * 128);

        for (int j = 0; j < cend; j += 16) {
            int jn = (j + 16 < cend) ? j + 16 : j;     // wave-uniform select
            int   sn0 = __shfl(me.x, jn + grp, 64);
            float wn0 = __shfl(mw,  jn + grp, 64);
            int   sn1 = __shfl(me.x, jn + 8 + grp, 64);
            float wn1 = __shfl(mw,  jn + 8 + grp, 64);
            uint4 rn0 = *(const uint4*)(Hfl + (size_t)sn0 * 128);  // issued before
            uint4 rn1 = *(const uint4*)(Hfl + (size_t)sn1 * 128);  // consuming r0/r1
            acc[0] = fmaf(bflo(r0.x), w0, acc[0]); acc[1] = fmaf(bfhi(r0.x), w0, acc[1]);
            acc[2] = fmaf(bflo(r0.y), w0, acc[2]); acc[3] = fmaf(bfhi(r0.y), w0, acc[3]);
            acc[4] = fmaf(bflo(r0.z), w0, acc[4]); acc[5] = fmaf(bfhi(r0.z), w0, acc[5]);
            acc[6] = fmaf(bflo(r0.w), w0, acc[6]); acc[7] = fmaf(bfhi(r0.w), w0, acc[7]);
            acc[0] = fmaf(bflo(r1.x), w1, acc[0]); acc[1] = fmaf(bfhi(r1.x), w1, acc[1]);
            acc[2] = fmaf(bflo(r1.y), w1, acc[2]); acc[3] = fmaf(bfhi(r1.y), w1, acc[3]);
            acc[4] = fmaf(bflo(r1.z), w1, acc[4]); acc[5] = fmaf(bfhi(r1.z), w1, acc[5]);
            acc[6] = fmaf(bflo(r1.w), w1, acc[6]); acc[7] = fmaf(bfhi(r1.w), w1, acc[7]);
            r0 = rn0; r1 = rn1; w0 = wn0; w1 = wn1;
        }
    }
    // reduce across the 8 edge-groups
#pragma unroll
    for (int k = 0; k < 8; k++) {
        acc[k] += __shfl_xor(acc[k], 8, 64);
        acc[k] += __shfl_xor(acc[k], 16, 64);
        acc[k] += __shfl_xor(acc[k], 32, 64);
    }
    // self-loop + bias + relu (8 contiguous features per fl-lane, this half)
    float dd = dis[nd], sn = dd * dd;
    uint4 rs = *(const uint4*)(Hfl + (size_t)nd * 128);
    float4 bb0 = ((const float4*)bias)[half * 16 + fl * 2];
    float4 bb1 = ((const float4*)bias)[half * 16 + fl * 2 + 1];
    acc[0] = fmaf(bflo(rs.x), sn, acc[0]) + bb0.x;
    acc[1] = fmaf(bfhi(rs.x), sn, acc[1]) + bb0.y;
    acc[2] = fmaf(bflo(rs.y), sn, acc[2]) + bb0.z;
    acc[3] = fmaf(bfhi(rs.y), sn, acc[3]) + bb0.w;
    acc[4] = fmaf(bflo(rs.z), sn, acc[4]) + bb1.x;
    acc[5] = fmaf(bfhi(rs.z), sn, acc[5]) + bb1.y;
    acc[6] = fmaf(bflo(rs.w), sn, acc[6]) + bb1.z;
    acc[7] = fmaf(bfhi(rs.w), sn, acc[7]) + bb1.w;
#pragma unroll
    for (int k = 0; k < 8; k++) acc[k] = acc[k] > 0.f ? acc[k] : 0.f;

    if (node < n && grp == 0) {
        uint4 pk;
        pk.x = ((unsigned)f2bf(acc[1]) << 16) | (unsigned)f2bf(acc[0]);
        pk.y = ((unsigned)f2bf(acc[3]) << 16) | (unsigned)f2bf(acc[2]);
        pk.z = ((unsigned)f2bf(acc[5]) << 16) | (unsigned)f2bf(acc[4]);
        pk.w = ((unsigned)f2bf(acc[7]) << 16) | (unsigned)f2bf(acc[6]);
        *(uint4*)(outb + (size_t)node * 128 + half * 64 + fl * 8) = pk;
    }
}

// ---- JK head (MFMA): out = log_softmax((x1+x2) @ lw + lb) -----------------
// Block = 64 nodes, 4 waves x 16 rows. A = x1+x2 split hi/lo bf16 in LDS;
// B = lwt split hi/lo (48 padded cols). 3 MFMAs per (kt,nt) give
// hi*hi + hi*lo + lo*hi  (~2^-16 rel error). C layout: col = nt*16 + mrow,
// row = wave*16 + quad*4 + r. Row-softmax via in-quad shuffles (xor 1,2,4,8).
__global__ __launch_bounds__(256) void head_k(const unsigned short* __restrict__ x1b,
                                              const unsigned short* __restrict__ x2b,
                                              const unsigned short* __restrict__ lwt_hi,
                                              const unsigned short* __restrict__ lwt_lo,
                                              const float* __restrict__ lb,
                                              float* __restrict__ out, int n) {
    __shared__ unsigned short Ah[64][136];   // +8 pad: conflict-free b128 reads
    __shared__ unsigned short Al[64][136];
    __shared__ unsigned short Bh[48][136];
    __shared__ unsigned short Bl[48][136];
    const int tid = threadIdx.x;
    const int wave = tid >> 6, lane = tid & 63;
    const int quad = lane >> 4, mrow = lane & 15;
    const int base = blockIdx.x * 64;

    // stage A: JK sum, split into hi+lo bf16
    for (int i = tid; i < 1024; i += 256) {
        int row = i >> 4, oct = i & 15;
        int node = base + row; int nd = node < n ? node : n - 1;
        uint4 u1 = *(const uint4*)(x1b + (size_t)nd * 128 + oct * 8);
        uint4 u2 = *(const uint4*)(x2b + (size_t)nd * 128 + oct * 8);
        unsigned uu1[4] = {u1.x, u1.y, u1.z, u1.w};
        unsigned uu2[4] = {u2.x, u2.y, u2.z, u2.w};
        union { short8 v; unsigned short u[8]; } H, L;
#pragma unroll
        for (int q = 0; q < 4; q++) {
            float vl = bflo(uu1[q]) + bflo(uu2[q]);
            float vh = bfhi(uu1[q]) + bfhi(uu2[q]);
            unsigned short hl = f2bf(vl), hh = f2bf(vh);
            H.u[q * 2]     = hl;  L.u[q * 2]     = f2bf(vl - bf2f(hl));
            H.u[q * 2 + 1] = hh;  L.u[q * 2 + 1] = f2bf(vh - bf2f(hh));
        }
        *(short8*)&Ah[row][oct * 8] = H.v;
        *(short8*)&Al[row][oct * 8] = L.v;
    }
    // stage B: pre-split lw^T (48x128)
    for (int i = tid; i < 768; i += 256) {
        int row = i >> 4, oct = i & 15;
        *(short8*)&Bh[row][oct * 8] = *(const short8*)&lwt_hi[row * 128 + oct * 8];
        *(short8*)&Bl[row][oct * 8] = *(const short8*)&lwt_lo[row * 128 + oct * 8];
    }
    __syncthreads();

    f32x4 acc[3];
#pragma unroll
    for (int nt = 0; nt < 3; nt++) acc[nt] = (f32x4){0.f, 0.f, 0.f, 0.f};
#pragma unroll
    for (int kt = 0; kt < 128; kt += 32) {
        short8 ah = *(short8*)&Ah[wave * 16 + mrow][kt + quad * 8];
        short8 al = *(short8*)&Al[wave * 16 + mrow][kt + quad * 8];
#pragma unroll
        for (int nt = 0; nt < 3; nt++) {
            short8 bh = *(short8*)&Bh[nt * 16 + mrow][kt + quad * 8];
            short8 bl = *(short8*)&Bl[nt * 16 + mrow][kt + quad * 8];
            acc[nt] = __builtin_amdgcn_mfma_f32_16x16x32_bf16(ah, bh, acc[nt], 0, 0, 0);
            acc[nt] = __builtin_amdgcn_mfma_f32_16x16x32_bf16(ah, bl, acc[nt], 0, 0, 0);
            acc[nt] = __builtin_amdgcn_mfma_f32_16x16x32_bf16(al, bh, acc[nt], 0, 0, 0);
        }
    }

    // bias + row-wise log_softmax. cols: mrow, 16+mrow always valid (<41);
    // 32+mrow valid iff mrow<9.
    const bool v2ok = (mrow < 9);
    const float lb0 = lb[mrow];
    const float lb1 = lb[16 + mrow];
    const float lb2 = v2ok ? lb[32 + mrow] : 0.f;
#pragma unroll
    for (int r = 0; r < 4; r++) {
        int node = base + wave * 16 + quad * 4 + r;
        float v0 = acc[0][r] + lb0;
        float v1 = acc[1][r] + lb1;
        float v2 = v2ok ? acc[2][r] + lb2 : -INFINITY;
        float m = fmaxf(fmaxf(v0, v1), v2);
#pragma unroll
        for (int off = 1; off < 16; off <<= 1) m = fmaxf(m, __shfl_xor(m, off, 64));
        float e = expf(v0 - m) + expf(v1 - m) + (v2ok ? expf(v2 - m) : 0.f);
#pragma unroll
        for (int off = 1; off < 16; off <<= 1) e += __shfl_xor(e, off, 64);
        float lse = m + logf(e);
        if (node < n) {
            out[(size_t)node * 41 + mrow] = v0 - lse;
            out[(size_t)node * 41 + 16 + mrow] = v1 - lse;
            if (v2ok) out[(size_t)node * 41 + 32 + mrow] = v2 - lse;
        }
    }
}

extern "C" void kernel_launch(void* const* d_in, const int* in_sizes, int n_in,
                              void* d_out, int out_size, void* d_ws, size_t ws_size,
                              hipStream_t stream) {
    const float* x  = (const float*)d_in[0];
    const int*   ei = (const int*)d_in[1];
    const float* W1 = (const float*)d_in[2];
    const float* b1 = (const float*)d_in[3];
    const float* W2 = (const float*)d_in[4];
    const float* b2 = (const float*)d_in[5];
    const float* lw = (const float*)d_in[6];
    const float* lb = (const float*)d_in[7];
    float* out = (float*)d_out;

    const int n = in_sizes[0] / 256;   // 100000
    const int E = in_sizes[1] / 2;     // 1600000
    const int* src = ei;
    const int* dst = ei + E;

    // workspace layout (~92 MB)
    int*   cnt     = (int*)d_ws;                       // NPAD
    int*   offs    = cnt + NPAD;                       // NPAD
    int*   cursor  = offs + NPAD;                      // NPAD
    int*   partial = cursor + NPAD;                    // 1024
    float* dis     = (float*)(partial + 1024);         // NPAD
    size_t Epad    = ((size_t)E + 255) & ~(size_t)255;
    int2*  eadj    = (int2*)(dis + NPAD);              // Epad pairs (8 B)
    unsigned short* Wt1 = (unsigned short*)(eadj + Epad);  // 256*128 bf16
    unsigned short* Wt2 = Wt1 + 256 * 128;                 // 128*128 bf16
    unsigned short* Hb  = Wt2 + 128 * 128;                 // n*128 bf16
    unsigned short* X1b = Hb + (size_t)n * 128;            // n*128 bf16
    unsigned short* X2b = X1b + (size_t)n * 128;           // n*128 bf16
    unsigned short* Lh  = X2b + (size_t)n * 128;           // 48*128 bf16 (lw hi)
    unsigned short* Ll  = Lh + 48 * 128;                   // 48*128 bf16 (lw lo)

    const int nscan = (n + CHUNK - 1) / CHUNK;
    const int histB = (E + 255) / 256;                 // 6250
    const int wcastB = (256 * 128 + 128 * 128 + 48 * 128 + 255) / 256;  // 216
    const int gemmB = (n + 63) / 64;                   // 1563
    const int NB = (n + 3) / 4;                        // node-blocks (4/block)
    const int gathB = 8 * ((NB + 3) / 4);              // 8 XCD-combos

    hipMemsetAsync(cnt, 0, (size_t)n * sizeof(int), stream);

    // CSR hist + weight prep (independent, one low-resource dispatch)
    mega1<<<histB + wcastB, 256, 0, stream>>>(dst, cnt, E, histB, W1, Wt1, W2, Wt2,
                                              lw, Lh, Ll);
    scan_partial<<<nscan, 256, 0, stream>>>(cnt, partial, n);
    scan_small<<<1, 128, 0, stream>>>(partial, nscan);
    scan_final<<<nscan, 256, 0, stream>>>(cnt, partial, offs, cursor, dis, n);
    permute_all<<<histB, 256, 0, stream>>>(src, dst, dis, cursor, eadj, E);

    // layer 1: transform + aggregate (feature-split, XCD-pinned)
    gemm1_k<<<gemmB, 256, 0, stream>>>(x, Wt1, Hb, n);
    gather_h<<<gathB, 256, 0, stream>>>(Hb, eadj, offs, cnt, dis, b1, X1b, n);

    // layer 2 transform + aggregate
    gemm2_k<<<gemmB, 256, 0, stream>>>(X1b, Wt2, Hb, n);
    gather_h<<<gathB, 256, 0, stream>>>(Hb, eadj, offs, cnt, dis, b2, X2b, n);

    // JK + linear + log_softmax (MFMA, bf16x2 split)
    head_k<<<gemmB, 256, 0, stream>>>(X1b, X2b, Lh, Ll, lb, out, n);
}

// Round 6
// 544.128 us; speedup vs baseline: 1.1775x; 1.0146x over previous
//
#include <hip/hip_runtime.h>
#include <math.h>

// ---------------------------------------------------------------------------
// JKNet: 2-layer GCN (sym-norm A+I) + sum-JK + linear + log_softmax.
// Round 12: gather_h instruction diet. Counters (r11): VALUBusy 71%, FETCH at
// the compulsory 176MB floor => instruction-bound, ~420 VALU instrs/wave for
// avg 16 edges (epilogue-heavy). Changes: pk-FMA main loop (16 fmaf -> 8
// v_pk_fma_f32), pk reduce/epilogue, v_cvt_pk_bf16_f32 pack (4 instrs vs 32).
// Memory pattern bit-identical to r11. Also: scan_small folded into
// scan_final (one fewer dispatch). Everything else frozen.
// ---------------------------------------------------------------------------

#define NPAD (1 << 17)   // padded node-array stride (N=100000)
#define CHUNK 1024       // scan chunk (elements per block)

typedef __attribute__((ext_vector_type(8))) short short8;
typedef __attribute__((ext_vector_type(4))) float f32x4;
typedef __attribute__((ext_vector_type(2))) float f32x2;

__device__ inline unsigned short f2bf(float f) {
    unsigned u = __builtin_bit_cast(unsigned, f);
    return (unsigned short)((u + 0x7fffu + ((u >> 16) & 1u)) >> 16);
}
__device__ inline float bf2f(unsigned short h) {
    return __builtin_bit_cast(float, (unsigned)h << 16);
}
__device__ inline float bflo(unsigned u) { return __builtin_bit_cast(float, u << 16); }
__device__ inline float bfhi(unsigned u) { return __builtin_bit_cast(float, u & 0xffff0000u); }
__device__ inline f32x2 up2(unsigned u) {
    f32x2 r; r.x = bflo(u); r.y = bfhi(u); return r;
}

// ---- CSR build + weight prep ----------------------------------------------

// Union dispatch: hist | W1/W2 cast-transpose | lw split-transpose.
// All parts low-resource (no LDS, few VGPRs) -> union is safe.
__global__ void mega1(const int* __restrict__ dst, int* __restrict__ cnt, int E, int histB,
                      const float* __restrict__ W1, unsigned short* __restrict__ Wt1,
                      const float* __restrict__ W2, unsigned short* __restrict__ Wt2,
                      const float* __restrict__ lw, unsigned short* __restrict__ lwt_hi,
                      unsigned short* __restrict__ lwt_lo) {
    int b = blockIdx.x;
    if (b < histB) {
        int e = b * 256 + threadIdx.x;
        if (e < E) atomicAdd(&cnt[dst[e]], 1);
    } else {
        int i = (b - histB) * 256 + threadIdx.x;
        if (i < 256 * 128) {
            int k = i >> 7, nn = i & 127;
            Wt1[nn * 256 + k] = f2bf(W1[i]);
        } else if (i < 256 * 128 + 128 * 128) {
            int j = i - 256 * 128;
            int k = j >> 7, nn = j & 127;
            Wt2[nn * 128 + k] = f2bf(W2[j]);
        } else {
            int j = i - (256 * 128 + 128 * 128);
            if (j < 48 * 128) {
                int c = j >> 7, k = j & 127;       // lwt[c][k] = lw[k][c], pad c>=41
                float wv = (c < 41) ? lw[k * 41 + c] : 0.f;
                unsigned short hi = f2bf(wv);
                lwt_hi[c * 128 + k] = hi;
                lwt_lo[c * 128 + k] = f2bf(wv - bf2f(hi));
            }
        }
    }
}

__global__ void scan_partial(const int* __restrict__ cnt, int* __restrict__ partial, int n) {
    __shared__ int sdata[4];
    int b = blockIdx.x, t = threadIdx.x;
    int base = b * CHUNK;
    int sum = 0;
    for (int i = t; i < CHUNK; i += 256) {
        int idx = base + i;
        if (idx < n) sum += cnt[idx];
    }
#pragma unroll
    for (int off = 32; off > 0; off >>= 1) sum += __shfl_down(sum, off, 64);
    if ((t & 63) == 0) sdata[t >> 6] = sum;
    __syncthreads();
    if (t == 0) partial[b] = sdata[0] + sdata[1] + sdata[2] + sdata[3];
}

// scan_final with the small cross-block scan inlined (each block redundantly
// scans the <=128 partial sums in LDS -- replaces the scan_small dispatch).
__global__ void scan_final(const int* __restrict__ cnt, const int* __restrict__ partial,
                           int* __restrict__ offs, int* __restrict__ cursor,
                           float* __restrict__ dis, int n, int nscan) {
    __shared__ int sm[128];
    __shared__ int wsum[4];
    int b = blockIdx.x, t = threadIdx.x;
    int lane = t & 63, w = t >> 6;

    // inline exclusive scan of block sums (nscan <= 128)
    int pv = 0, px = 0;
    if (t < 128) {
        pv = (t < nscan) ? partial[t] : 0;
        px = pv;
        sm[t] = px;
    }
    __syncthreads();
    for (int off = 1; off < 128; off <<= 1) {
        int y = (t >= off && t < 128) ? sm[t - off] : 0;
        __syncthreads();
        if (t < 128) { px += y; sm[t] = px; }
        __syncthreads();
    }
    if (t < 128) sm[t] = px - pv;   // exclusive
    __syncthreads();
    const int bbase = sm[b];

    int base = b * CHUNK + t * 4;
    int v[4];
#pragma unroll
    for (int j = 0; j < 4; j++) v[j] = (base + j < n) ? cnt[base + j] : 0;
    int s4 = v[0] + v[1] + v[2] + v[3];
    int inc = s4;
#pragma unroll
    for (int off = 1; off < 64; off <<= 1) {
        int x = __shfl_up(inc, off, 64);
        if (lane >= off) inc += x;
    }
    if (lane == 63) wsum[w] = inc;
    __syncthreads();
    int woff = 0;
    for (int i = 0; i < 4; i++) if (i < w) woff += wsum[i];
    int pos = bbase + woff + (inc - s4);
#pragma unroll
    for (int j = 0; j < 4; j++) {
        int idx = base + j;
        if (idx < n) {
            offs[idx] = pos;
            cursor[idx] = pos;
            dis[idx] = rsqrtf((float)(v[j] + 1));  // deg = incoming + self-loop
            pos += v[j];
        }
    }
}

// Single-pass permute: standalone (28 VGPR, no LDS -> full occupancy).
__global__ void permute_all(const int* __restrict__ src, const int* __restrict__ dst,
                            const float* __restrict__ dis,
                            int* __restrict__ cursor, int2* __restrict__ eadj, int E) {
    int e = blockIdx.x * 256 + threadIdx.x;
    if (e < E) {
        int d = dst[e];
        int s = src[e];
        int pos = atomicAdd(&cursor[d], 1);
        eadj[pos] = make_int2(s, __float_as_int(dis[s] * dis[d]));
    }
}

// ---- MFMA GEMM body: Hb[n,128](bf16) = A[n,K] @ W[K,128] ------------------
template<bool ABF16>
__device__ void gemm_body(int bid, const void* __restrict__ Ap,
                          const unsigned short* __restrict__ Wt,
                          unsigned short* __restrict__ Hb,
                          int n, int K, unsigned short* bs) {
    const int tid = threadIdx.x;
    const int wave = tid >> 6, lane = tid & 63;
    const int quad = lane >> 4, mrow = lane & 15;
    const int arow_g = bid * 64 + wave * 16 + mrow;
    const int arow = arow_g < n ? arow_g : n - 1;

    f32x4 acc[8];
#pragma unroll
    for (int t = 0; t < 8; t++) acc[t] = (f32x4){0.f, 0.f, 0.f, 0.f};

    const float* Af = (const float*)Ap;
    const unsigned short* Ab = (const unsigned short*)Ap;

    for (int kc = 0; kc < K; kc += 128) {
        __syncthreads();
        for (int i = tid; i < 2048; i += 256) {
            int row = i >> 4, c8 = i & 15;
            *(short8*)&bs[row * 136 + c8 * 8] = *(const short8*)&Wt[row * K + kc + c8 * 8];
        }
        __syncthreads();
#pragma unroll
        for (int kt = 0; kt < 128; kt += 32) {
            union { short8 v; unsigned short u[8]; } A;
            if (ABF16) {
                A.v = *(const short8*)&Ab[(size_t)arow * K + kc + kt + quad * 8];
            } else {
                const float* ap = &Af[(size_t)arow * K + kc + kt + quad * 8];
                float4 p0 = *(const float4*)ap;
                float4 p1 = *(const float4*)(ap + 4);
                A.u[0] = f2bf(p0.x); A.u[1] = f2bf(p0.y);
                A.u[2] = f2bf(p0.z); A.u[3] = f2bf(p0.w);
                A.u[4] = f2bf(p1.x); A.u[5] = f2bf(p1.y);
                A.u[6] = f2bf(p1.z); A.u[7] = f2bf(p1.w);
            }
#pragma unroll
            for (int nt = 0; nt < 8; nt++) {
                short8 B = *(const short8*)&bs[(nt * 16 + mrow) * 136 + kt + quad * 8];
                acc[nt] = __builtin_amdgcn_mfma_f32_16x16x32_bf16(A.v, B, acc[nt], 0, 0, 0);
            }
        }
    }
    const int drow0 = bid * 64 + wave * 16 + quad * 4;
#pragma unroll
    for (int r = 0; r < 4; r++) {
        int dr = drow0 + r;
        if (dr < n) {
#pragma unroll
            for (int nt = 0; nt < 8; nt++)
                Hb[(size_t)dr * 128 + nt * 16 + mrow] = f2bf(acc[nt][r]);
        }
    }
}

__global__ __launch_bounds__(256) void gemm1_k(const float* __restrict__ x,
                                               const unsigned short* __restrict__ Wt1,
                                               unsigned short* __restrict__ Hb, int n) {
    __shared__ unsigned short bs[128 * 136];
    gemm_body<false>(blockIdx.x, x, Wt1, Hb, n, 256, bs);
}

__global__ __launch_bounds__(256) void gemm2_k(const unsigned short* __restrict__ X1b,
                                               const unsigned short* __restrict__ Wt2,
                                               unsigned short* __restrict__ Hb, int n) {
    __shared__ unsigned short bs[128 * 136];
    gemm_body<true>(blockIdx.x, X1b, Wt2, Hb, n, 128, bs);
}

// ---- CSR gather, half-feature, XCD-pinned, packed-f32 math ----------------
// Block decode: xcd = bid%8 (native round-robin); half = xcd>>2 selects
// features [half*64, half*64+64); nb = (bid>>3)*4 + (xcd&3) is the node-block.
// Wave = 1 node. lane = grp*8 + fl: 8 edge-groups x 8 feature-lanes; a group's
// 8 lanes read one 128B half-row (exactly one cache line). Pipeline depth-2,
// 16 edges per stage. f32x2 accumulators -> v_pk_fma_f32 (8 instrs/16 edges),
// pk reduce/epilogue, v_cvt_pk_bf16_f32 pack.

#define PKC(R, W) {                                          \
    f32x2 _w; _w.x = (W); _w.y = (W);                        \
    a0 = __builtin_elementwise_fma(up2(R.x), _w, a0);        \
    a1 = __builtin_elementwise_fma(up2(R.y), _w, a1);        \
    a2 = __builtin_elementwise_fma(up2(R.z), _w, a2);        \
    a3 = __builtin_elementwise_fma(up2(R.w), _w, a3);        \
}

#define RED3(A) {                                            \
    f32x2 _t;                                                \
    _t.x = __shfl_xor(A.x, 8, 64);  _t.y = __shfl_xor(A.y, 8, 64);  A = A + _t; \
    _t.x = __shfl_xor(A.x, 16, 64); _t.y = __shfl_xor(A.y, 16, 64); A = A + _t; \
    _t.x = __shfl_xor(A.x, 32, 64); _t.y = __shfl_xor(A.y, 32, 64); A = A + _t; \
}

__global__ __launch_bounds__(256) void gather_h(const unsigned short* __restrict__ Hb,
                                                const int2* __restrict__ eadj,
                                                const int* __restrict__ offs,
                                                const int* __restrict__ cnt,
                                                const float* __restrict__ dis,
                                                const float* __restrict__ bias,
                                                unsigned short* __restrict__ outb,
                                                int n) {
    const int b = blockIdx.x;
    const int xcd = b & 7;
    const int half = xcd >> 2;
    const int nb = ((b >> 3) << 2) | (xcd & 3);
    const int w = threadIdx.x >> 6, lane = threadIdx.x & 63;
    const int grp = lane >> 3, fl = lane & 7;
    const int node = nb * 4 + w;
    const int nd = node < n ? node : n - 1;
    const int st = offs[nd], c = cnt[nd];
    const unsigned short* Hfl = Hb + half * 64 + fl * 8;

    f32x2 a0 = (f32x2){0.f, 0.f}, a1 = (f32x2){0.f, 0.f};
    f32x2 a2 = (f32x2){0.f, 0.f}, a3 = (f32x2){0.f, 0.f};

    const int2* ep = eadj + st;
    for (int kk = 0; kk < c; kk += 64) {
        int li = kk + lane;
        int2 me = ep[li < c ? li : c - 1];             // c>0 guaranteed in loop
        float mw = li < c ? __int_as_float(me.y) : 0.f;
        int cend = (c - kk) < 64 ? (c - kk) : 64;

        // prologue: edges grp / 8+grp
        int   s0 = __shfl(me.x, grp, 64);
        float w0 = __shfl(mw,  grp, 64);
        int   s1 = __shfl(me.x, 8 + grp, 64);
        float w1 = __shfl(mw,  8 + grp, 64);
        uint4 r0 = *(const uint4*)(Hfl + (size_t)s0 * 128);
        uint4 r1 = *(const uint4*)(Hfl + (size_t)s1 * 128);

        for (int j = 0; j < cend; j += 16) {
            int jn = (j + 16 < cend) ? j + 16 : j;     // wave-uniform select
            int   sn0 = __shfl(me.x, jn + grp, 64);
            float wn0 = __shfl(mw,  jn + grp, 64);
            int   sn1 = __shfl(me.x, jn + 8 + grp, 64);
            float wn1 = __shfl(mw,  jn + 8 + grp, 64);
            uint4 rn0 = *(const uint4*)(Hfl + (size_t)sn0 * 128);  // issued before
            uint4 rn1 = *(const uint4*)(Hfl + (size_t)sn1 * 128);  // consuming r0/r1
            PKC(r0, w0);
            PKC(r1, w1);
            r0 = rn0; r1 = rn1; w0 = wn0; w1 = wn1;
        }
    }
    // reduce across the 8 edge-groups (pk adds)
    RED3(a0); RED3(a1); RED3(a2); RED3(a3);

    // self-loop + bias + relu (8 contiguous features per fl-lane, this half)
    float dd = dis[nd], sn = dd * dd;
    uint4 rs = *(const uint4*)(Hfl + (size_t)nd * 128);
    float4 bb0 = ((const float4*)bias)[half * 16 + fl * 2];
    float4 bb1 = ((const float4*)bias)[half * 16 + fl * 2 + 1];
    f32x2 s2; s2.x = sn; s2.y = sn;
    f32x2 bv;
    a0 = __builtin_elementwise_fma(up2(rs.x), s2, a0); bv.x = bb0.x; bv.y = bb0.y; a0 = a0 + bv;
    a1 = __builtin_elementwise_fma(up2(rs.y), s2, a1); bv.x = bb0.z; bv.y = bb0.w; a1 = a1 + bv;
    a2 = __builtin_elementwise_fma(up2(rs.z), s2, a2); bv.x = bb1.x; bv.y = bb1.y; a2 = a2 + bv;
    a3 = __builtin_elementwise_fma(up2(rs.w), s2, a3); bv.x = bb1.z; bv.y = bb1.w; a3 = a3 + bv;
    f32x2 zz = (f32x2){0.f, 0.f};
    a0 = __builtin_elementwise_max(a0, zz);
    a1 = __builtin_elementwise_max(a1, zz);
    a2 = __builtin_elementwise_max(a2, zz);
    a3 = __builtin_elementwise_max(a3, zz);

    if (node < n && grp == 0) {
        uint4 pk;
        asm("v_cvt_pk_bf16_f32 %0, %1, %2" : "=v"(pk.x) : "v"(a0.x), "v"(a0.y));
        asm("v_cvt_pk_bf16_f32 %0, %1, %2" : "=v"(pk.y) : "v"(a1.x), "v"(a1.y));
        asm("v_cvt_pk_bf16_f32 %0, %1, %2" : "=v"(pk.z) : "v"(a2.x), "v"(a2.y));
        asm("v_cvt_pk_bf16_f32 %0, %1, %2" : "=v"(pk.w) : "v"(a3.x), "v"(a3.y));
        *(uint4*)(outb + (size_t)node * 128 + half * 64 + fl * 8) = pk;
    }
}

// ---- JK head (MFMA): out = log_softmax((x1+x2) @ lw + lb) -----------------
// Block = 64 nodes, 4 waves x 16 rows. A = x1+x2 split hi/lo bf16 in LDS;
// B = lwt split hi/lo (48 padded cols). 3 MFMAs per (kt,nt) give
// hi*hi + hi*lo + lo*hi  (~2^-16 rel error). C layout: col = nt*16 + mrow,
// row = wave*16 + quad*4 + r. Row-softmax via in-quad shuffles (xor 1,2,4,8).
__global__ __launch_bounds__(256) void head_k(const unsigned short* __restrict__ x1b,
                                              const unsigned short* __restrict__ x2b,
                                              const unsigned short* __restrict__ lwt_hi,
                                              const unsigned short* __restrict__ lwt_lo,
                                              const float* __restrict__ lb,
                                              float* __restrict__ out, int n) {
    __shared__ unsigned short Ah[64][136];   // +8 pad: conflict-free b128 reads
    __shared__ unsigned short Al[64][136];
    __shared__ unsigned short Bh[48][136];
    __shared__ unsigned short Bl[48][136];
    const int tid = threadIdx.x;
    const int wave = tid >> 6, lane = tid & 63;
    const int quad = lane >> 4, mrow = lane & 15;
    const int base = blockIdx.x * 64;

    // stage A: JK sum, split into hi+lo bf16
    for (int i = tid; i < 1024; i += 256) {
        int row = i >> 4, oct = i & 15;
        int node = base + row; int nd = node < n ? node : n - 1;
        uint4 u1 = *(const uint4*)(x1b + (size_t)nd * 128 + oct * 8);
        uint4 u2 = *(const uint4*)(x2b + (size_t)nd * 128 + oct * 8);
        unsigned uu1[4] = {u1.x, u1.y, u1.z, u1.w};
        unsigned uu2[4] = {u2.x, u2.y, u2.z, u2.w};
        union { short8 v; unsigned short u[8]; } H, L;
#pragma unroll
        for (int q = 0; q < 4; q++) {
            float vl = bflo(uu1[q]) + bflo(uu2[q]);
            float vh = bfhi(uu1[q]) + bfhi(uu2[q]);
            unsigned short hl = f2bf(vl), hh = f2bf(vh);
            H.u[q * 2]     = hl;  L.u[q * 2]     = f2bf(vl - bf2f(hl));
            H.u[q * 2 + 1] = hh;  L.u[q * 2 + 1] = f2bf(vh - bf2f(hh));
        }
        *(short8*)&Ah[row][oct * 8] = H.v;
        *(short8*)&Al[row][oct * 8] = L.v;
    }
    // stage B: pre-split lw^T (48x128)
    for (int i = tid; i < 768; i += 256) {
        int row = i >> 4, oct = i & 15;
        *(short8*)&Bh[row][oct * 8] = *(const short8*)&lwt_hi[row * 128 + oct * 8];
        *(short8*)&Bl[row][oct * 8] = *(const short8*)&lwt_lo[row * 128 + oct * 8];
    }
    __syncthreads();

    f32x4 acc[3];
#pragma unroll
    for (int nt = 0; nt < 3; nt++) acc[nt] = (f32x4){0.f, 0.f, 0.f, 0.f};
#pragma unroll
    for (int kt = 0; kt < 128; kt += 32) {
        short8 ah = *(short8*)&Ah[wave * 16 + mrow][kt + quad * 8];
        short8 al = *(short8*)&Al[wave * 16 + mrow][kt + quad * 8];
#pragma unroll
        for (int nt = 0; nt < 3; nt++) {
            short8 bh = *(short8*)&Bh[nt * 16 + mrow][kt + quad * 8];
            short8 bl = *(short8*)&Bl[nt * 16 + mrow][kt + quad * 8];
            acc[nt] = __builtin_amdgcn_mfma_f32_16x16x32_bf16(ah, bh, acc[nt], 0, 0, 0);
            acc[nt] = __builtin_amdgcn_mfma_f32_16x16x32_bf16(ah, bl, acc[nt], 0, 0, 0);
            acc[nt] = __builtin_amdgcn_mfma_f32_16x16x32_bf16(al, bh, acc[nt], 0, 0, 0);
        }
    }

    // bias + row-wise log_softmax. cols: mrow, 16+mrow always valid (<41);
    // 32+mrow valid iff mrow<9.
    const bool v2ok = (mrow < 9);
    const float lb0 = lb[mrow];
    const float lb1 = lb[16 + mrow];
    const float lb2 = v2ok ? lb[32 + mrow] : 0.f;
#pragma unroll
    for (int r = 0; r < 4; r++) {
        int node = base + wave * 16 + quad * 4 + r;
        float v0 = acc[0][r] + lb0;
        float v1 = acc[1][r] + lb1;
        float v2 = v2ok ? acc[2][r] + lb2 : -INFINITY;
        float m = fmaxf(fmaxf(v0, v1), v2);
#pragma unroll
        for (int off = 1; off < 16; off <<= 1) m = fmaxf(m, __shfl_xor(m, off, 64));
        float e = expf(v0 - m) + expf(v1 - m) + (v2ok ? expf(v2 - m) : 0.f);
#pragma unroll
        for (int off = 1; off < 16; off <<= 1) e += __shfl_xor(e, off, 64);
        float lse = m + logf(e);
        if (node < n) {
            out[(size_t)node * 41 + mrow] = v0 - lse;
            out[(size_t)node * 41 + 16 + mrow] = v1 - lse;
            if (v2ok) out[(size_t)node * 41 + 32 + mrow] = v2 - lse;
        }
    }
}

extern "C" void kernel_launch(void* const* d_in, const int* in_sizes, int n_in,
                              void* d_out, int out_size, void* d_ws, size_t ws_size,
                              hipStream_t stream) {
    const float* x  = (const float*)d_in[0];
    const int*   ei = (const int*)d_in[1];
    const float* W1 = (const float*)d_in[2];
    const float* b1 = (const float*)d_in[3];
    const float* W2 = (const float*)d_in[4];
    const float* b2 = (const float*)d_in[5];
    const float* lw = (const float*)d_in[6];
    const float* lb = (const float*)d_in[7];
    float* out = (float*)d_out;

    const int n = in_sizes[0] / 256;   // 100000
    const int E = in_sizes[1] / 2;     // 1600000
    const int* src = ei;
    const int* dst = ei + E;

    // workspace layout (~92 MB)
    int*   cnt     = (int*)d_ws;                       // NPAD
    int*   offs    = cnt + NPAD;                       // NPAD
    int*   cursor  = offs + NPAD;                      // NPAD
    int*   partial = cursor + NPAD;                    // 1024
    float* dis     = (float*)(partial + 1024);         // NPAD
    size_t Epad    = ((size_t)E + 255) & ~(size_t)255;
    int2*  eadj    = (int2*)(dis + NPAD);              // Epad pairs (8 B)
    unsigned short* Wt1 = (unsigned short*)(eadj + Epad);  // 256*128 bf16
    unsigned short* Wt2 = Wt1 + 256 * 128;                 // 128*128 bf16
    unsigned short* Hb  = Wt2 + 128 * 128;                 // n*128 bf16
    unsigned short* X1b = Hb + (size_t)n * 128;            // n*128 bf16
    unsigned short* X2b = X1b + (size_t)n * 128;           // n*128 bf16
    unsigned short* Lh  = X2b + (size_t)n * 128;           // 48*128 bf16 (lw hi)
    unsigned short* Ll  = Lh + 48 * 128;                   // 48*128 bf16 (lw lo)

    const int nscan = (n + CHUNK - 1) / CHUNK;         // 98 (<=128)
    const int histB = (E + 255) / 256;                 // 6250
    const int wcastB = (256 * 128 + 128 * 128 + 48 * 128 + 255) / 256;  // 216
    const int gemmB = (n + 63) / 64;                   // 1563
    const int NB = (n + 3) / 4;                        // node-blocks (4/block)
    const int gathB = 8 * ((NB + 3) / 4);              // 8 XCD-combos

    hipMemsetAsync(cnt, 0, (size_t)n * sizeof(int), stream);

    // CSR hist + weight prep (independent, one low-resource dispatch)
    mega1<<<histB + wcastB, 256, 0, stream>>>(dst, cnt, E, histB, W1, Wt1, W2, Wt2,
                                              lw, Lh, Ll);
    scan_partial<<<nscan, 256, 0, stream>>>(cnt, partial, n);
    scan_final<<<nscan, 256, 0, stream>>>(cnt, partial, offs, cursor, dis, n, nscan);
    permute_all<<<histB, 256, 0, stream>>>(src, dst, dis, cursor, eadj, E);

    // layer 1: transform + aggregate (feature-split, XCD-pinned)
    gemm1_k<<<gemmB, 256, 0, stream>>>(x, Wt1, Hb, n);
    gather_h<<<gathB, 256, 0, stream>>>(Hb, eadj, offs, cnt, dis, b1, X1b, n);

    // layer 2 transform + aggregate
    gemm2_k<<<gemmB, 256, 0, stream>>>(X1b, Wt2, Hb, n);
    gather_h<<<gathB, 256, 0, stream>>>(Hb, eadj, offs, cnt, dis, b2, X2b, n);

    // JK + linear + log_softmax (MFMA, bf16x2 split)
    head_k<<<gemmB, 256, 0, stream>>>(X1b, X2b, Lh, Ll, lb, out, n);
}

// Round 7
// 514.163 us; speedup vs baseline: 1.2461x; 1.0583x over previous
//
#include <hip/hip_runtime.h>
#include <math.h>

// ---------------------------------------------------------------------------
// JKNet: 2-layer GCN (sym-norm A+I) + sum-JK + linear + log_softmax.
// Round 13: de-atomic the permute. r12 counters: permute_all 95us with
// VALUBusy 0.6% -- each edge serialized on a ~900cy device-scope fabric
// atomic (cross-XCD coherent point) + dependent scatter. Fix: hist's
// atomicAdd already returns the edge's rank within its dst run; store it
// (rank[e], 6.4MB streaming). Permute becomes pos = offs[d] + rank[e]:
// zero atomics, cached offs read, fire-and-forget scatter. cursor array
// dead. Everything else frozen from r12.
// ---------------------------------------------------------------------------

#define NPAD (1 << 17)   // padded node-array stride (N=100000)
#define CHUNK 1024       // scan chunk (elements per block)

typedef __attribute__((ext_vector_type(8))) short short8;
typedef __attribute__((ext_vector_type(4))) float f32x4;
typedef __attribute__((ext_vector_type(2))) float f32x2;

__device__ inline unsigned short f2bf(float f) {
    unsigned u = __builtin_bit_cast(unsigned, f);
    return (unsigned short)((u + 0x7fffu + ((u >> 16) & 1u)) >> 16);
}
__device__ inline float bf2f(unsigned short h) {
    return __builtin_bit_cast(float, (unsigned)h << 16);
}
__device__ inline float bflo(unsigned u) { return __builtin_bit_cast(float, u << 16); }
__device__ inline float bfhi(unsigned u) { return __builtin_bit_cast(float, u & 0xffff0000u); }
__device__ inline f32x2 up2(unsigned u) {
    f32x2 r; r.x = bflo(u); r.y = bfhi(u); return r;
}

// ---- CSR build + weight prep ----------------------------------------------

// Union dispatch: hist(+rank) | W1/W2 cast-transpose | lw split-transpose.
// All parts low-resource (no LDS, few VGPRs) -> union is safe.
__global__ void mega1(const int* __restrict__ dst, int* __restrict__ cnt,
                      int* __restrict__ rank, int E, int histB,
                      const float* __restrict__ W1, unsigned short* __restrict__ Wt1,
                      const float* __restrict__ W2, unsigned short* __restrict__ Wt2,
                      const float* __restrict__ lw, unsigned short* __restrict__ lwt_hi,
                      unsigned short* __restrict__ lwt_lo) {
    int b = blockIdx.x;
    if (b < histB) {
        int e = b * 256 + threadIdx.x;
        if (e < E) rank[e] = atomicAdd(&cnt[dst[e]], 1);   // rank within dst run
    } else {
        int i = (b - histB) * 256 + threadIdx.x;
        if (i < 256 * 128) {
            int k = i >> 7, nn = i & 127;
            Wt1[nn * 256 + k] = f2bf(W1[i]);
        } else if (i < 256 * 128 + 128 * 128) {
            int j = i - 256 * 128;
            int k = j >> 7, nn = j & 127;
            Wt2[nn * 128 + k] = f2bf(W2[j]);
        } else {
            int j = i - (256 * 128 + 128 * 128);
            if (j < 48 * 128) {
                int c = j >> 7, k = j & 127;       // lwt[c][k] = lw[k][c], pad c>=41
                float wv = (c < 41) ? lw[k * 41 + c] : 0.f;
                unsigned short hi = f2bf(wv);
                lwt_hi[c * 128 + k] = hi;
                lwt_lo[c * 128 + k] = f2bf(wv - bf2f(hi));
            }
        }
    }
}

__global__ void scan_partial(const int* __restrict__ cnt, int* __restrict__ partial, int n) {
    __shared__ int sdata[4];
    int b = blockIdx.x, t = threadIdx.x;
    int base = b * CHUNK;
    int sum = 0;
    for (int i = t; i < CHUNK; i += 256) {
        int idx = base + i;
        if (idx < n) sum += cnt[idx];
    }
#pragma unroll
    for (int off = 32; off > 0; off >>= 1) sum += __shfl_down(sum, off, 64);
    if ((t & 63) == 0) sdata[t >> 6] = sum;
    __syncthreads();
    if (t == 0) partial[b] = sdata[0] + sdata[1] + sdata[2] + sdata[3];
}

// scan_final with the small cross-block scan inlined (each block redundantly
// scans the <=128 partial sums in LDS -- no scan_small dispatch).
__global__ void scan_final(const int* __restrict__ cnt, const int* __restrict__ partial,
                           int* __restrict__ offs,
                           float* __restrict__ dis, int n, int nscan) {
    __shared__ int sm[128];
    __shared__ int wsum[4];
    int b = blockIdx.x, t = threadIdx.x;
    int lane = t & 63, w = t >> 6;

    // inline exclusive scan of block sums (nscan <= 128)
    int pv = 0, px = 0;
    if (t < 128) {
        pv = (t < nscan) ? partial[t] : 0;
        px = pv;
        sm[t] = px;
    }
    __syncthreads();
    for (int off = 1; off < 128; off <<= 1) {
        int y = (t >= off && t < 128) ? sm[t - off] : 0;
        __syncthreads();
        if (t < 128) { px += y; sm[t] = px; }
        __syncthreads();
    }
    if (t < 128) sm[t] = px - pv;   // exclusive
    __syncthreads();
    const int bbase = sm[b];

    int base = b * CHUNK + t * 4;
    int v[4];
#pragma unroll
    for (int j = 0; j < 4; j++) v[j] = (base + j < n) ? cnt[base + j] : 0;
    int s4 = v[0] + v[1] + v[2] + v[3];
    int inc = s4;
#pragma unroll
    for (int off = 1; off < 64; off <<= 1) {
        int x = __shfl_up(inc, off, 64);
        if (lane >= off) inc += x;
    }
    if (lane == 63) wsum[w] = inc;
    __syncthreads();
    int woff = 0;
    for (int i = 0; i < 4; i++) if (i < w) woff += wsum[i];
    int pos = bbase + woff + (inc - s4);
#pragma unroll
    for (int j = 0; j < 4; j++) {
        int idx = base + j;
        if (idx < n) {
            offs[idx] = pos;
            dis[idx] = rsqrtf((float)(v[j] + 1));  // deg = incoming + self-loop
            pos += v[j];
        }
    }
}

// Atomic-free permute: pos = offs[d] + rank[e]. offs/dis are 400KB (L2-hot);
// the eadj scatter is fire-and-forget (no dependent op after the write).
__global__ void permute_all(const int* __restrict__ src, const int* __restrict__ dst,
                            const int* __restrict__ rank,
                            const float* __restrict__ dis,
                            const int* __restrict__ offs,
                            int2* __restrict__ eadj, int E) {
    int e = blockIdx.x * 256 + threadIdx.x;
    if (e < E) {
        int d = dst[e];
        int s = src[e];
        int pos = offs[d] + rank[e];
        eadj[pos] = make_int2(s, __float_as_int(dis[s] * dis[d]));
    }
}

// ---- MFMA GEMM body: Hb[n,128](bf16) = A[n,K] @ W[K,128] ------------------
template<bool ABF16>
__device__ void gemm_body(int bid, const void* __restrict__ Ap,
                          const unsigned short* __restrict__ Wt,
                          unsigned short* __restrict__ Hb,
                          int n, int K, unsigned short* bs) {
    const int tid = threadIdx.x;
    const int wave = tid >> 6, lane = tid & 63;
    const int quad = lane >> 4, mrow = lane & 15;
    const int arow_g = bid * 64 + wave * 16 + mrow;
    const int arow = arow_g < n ? arow_g : n - 1;

    f32x4 acc[8];
#pragma unroll
    for (int t = 0; t < 8; t++) acc[t] = (f32x4){0.f, 0.f, 0.f, 0.f};

    const float* Af = (const float*)Ap;
    const unsigned short* Ab = (const unsigned short*)Ap;

    for (int kc = 0; kc < K; kc += 128) {
        __syncthreads();
        for (int i = tid; i < 2048; i += 256) {
            int row = i >> 4, c8 = i & 15;
            *(short8*)&bs[row * 136 + c8 * 8] = *(const short8*)&Wt[row * K + kc + c8 * 8];
        }
        __syncthreads();
#pragma unroll
        for (int kt = 0; kt < 128; kt += 32) {
            union { short8 v; unsigned short u[8]; } A;
            if (ABF16) {
                A.v = *(const short8*)&Ab[(size_t)arow * K + kc + kt + quad * 8];
            } else {
                const float* ap = &Af[(size_t)arow * K + kc + kt + quad * 8];
                float4 p0 = *(const float4*)ap;
                float4 p1 = *(const float4*)(ap + 4);
                A.u[0] = f2bf(p0.x); A.u[1] = f2bf(p0.y);
                A.u[2] = f2bf(p0.z); A.u[3] = f2bf(p0.w);
                A.u[4] = f2bf(p1.x); A.u[5] = f2bf(p1.y);
                A.u[6] = f2bf(p1.z); A.u[7] = f2bf(p1.w);
            }
#pragma unroll
            for (int nt = 0; nt < 8; nt++) {
                short8 B = *(const short8*)&bs[(nt * 16 + mrow) * 136 + kt + quad * 8];
                acc[nt] = __builtin_amdgcn_mfma_f32_16x16x32_bf16(A.v, B, acc[nt], 0, 0, 0);
            }
        }
    }
    const int drow0 = bid * 64 + wave * 16 + quad * 4;
#pragma unroll
    for (int r = 0; r < 4; r++) {
        int dr = drow0 + r;
        if (dr < n) {
#pragma unroll
            for (int nt = 0; nt < 8; nt++)
                Hb[(size_t)dr * 128 + nt * 16 + mrow] = f2bf(acc[nt][r]);
        }
    }
}

__global__ __launch_bounds__(256) void gemm1_k(const float* __restrict__ x,
                                               const unsigned short* __restrict__ Wt1,
                                               unsigned short* __restrict__ Hb, int n) {
    __shared__ unsigned short bs[128 * 136];
    gemm_body<false>(blockIdx.x, x, Wt1, Hb, n, 256, bs);
}

__global__ __launch_bounds__(256) void gemm2_k(const unsigned short* __restrict__ X1b,
                                               const unsigned short* __restrict__ Wt2,
                                               unsigned short* __restrict__ Hb, int n) {
    __shared__ unsigned short bs[128 * 136];
    gemm_body<true>(blockIdx.x, X1b, Wt2, Hb, n, 128, bs);
}

// ---- CSR gather, half-feature, XCD-pinned, packed-f32 math ----------------
// Block decode: xcd = bid%8 (native round-robin); half = xcd>>2 selects
// features [half*64, half*64+64); nb = (bid>>3)*4 + (xcd&3) is the node-block.
// Wave = 1 node. lane = grp*8 + fl: 8 edge-groups x 8 feature-lanes; a group's
// 8 lanes read one 128B half-row (exactly one cache line). Pipeline depth-2,
// 16 edges per stage. f32x2 accumulators -> v_pk_fma_f32, pk reduce/epilogue,
// v_cvt_pk_bf16_f32 pack.

#define PKC(R, W) {                                          \
    f32x2 _w; _w.x = (W); _w.y = (W);                        \
    a0 = __builtin_elementwise_fma(up2(R.x), _w, a0);        \
    a1 = __builtin_elementwise_fma(up2(R.y), _w, a1);        \
    a2 = __builtin_elementwise_fma(up2(R.z), _w, a2);        \
    a3 = __builtin_elementwise_fma(up2(R.w), _w, a3);        \
}

#define RED3(A) {                                            \
    f32x2 _t;                                                \
    _t.x = __shfl_xor(A.x, 8, 64);  _t.y = __shfl_xor(A.y, 8, 64);  A = A + _t; \
    _t.x = __shfl_xor(A.x, 16, 64); _t.y = __shfl_xor(A.y, 16, 64); A = A + _t; \
    _t.x = __shfl_xor(A.x, 32, 64); _t.y = __shfl_xor(A.y, 32, 64); A = A + _t; \
}

__global__ __launch_bounds__(256) void gather_h(const unsigned short* __restrict__ Hb,
                                                const int2* __restrict__ eadj,
                                                const int* __restrict__ offs,
                                                const int* __restrict__ cnt,
                                                const float* __restrict__ dis,
                                                const float* __restrict__ bias,
                                                unsigned short* __restrict__ outb,
                                                int n) {
    const int b = blockIdx.x;
    const int xcd = b & 7;
    const int half = xcd >> 2;
    const int nb = ((b >> 3) << 2) | (xcd & 3);
    const int w = threadIdx.x >> 6, lane = threadIdx.x & 63;
    const int grp = lane >> 3, fl = lane & 7;
    const int node = nb * 4 + w;
    const int nd = node < n ? node : n - 1;
    const int st = offs[nd], c = cnt[nd];
    const unsigned short* Hfl = Hb + half * 64 + fl * 8;

    f32x2 a0 = (f32x2){0.f, 0.f}, a1 = (f32x2){0.f, 0.f};
    f32x2 a2 = (f32x2){0.f, 0.f}, a3 = (f32x2){0.f, 0.f};

    const int2* ep = eadj + st;
    for (int kk = 0; kk < c; kk += 64) {
        int li = kk + lane;
        int2 me = ep[li < c ? li : c - 1];             // c>0 guaranteed in loop
        float mw = li < c ? __int_as_float(me.y) : 0.f;
        int cend = (c - kk) < 64 ? (c - kk) : 64;

        // prologue: edges grp / 8+grp
        int   s0 = __shfl(me.x, grp, 64);
        float w0 = __shfl(mw,  grp, 64);
        int   s1 = __shfl(me.x, 8 + grp, 64);
        float w1 = __shfl(mw,  8 + grp, 64);
        uint4 r0 = *(const uint4*)(Hfl + (size_t)s0 * 128);
        uint4 r1 = *(const uint4*)(Hfl + (size_t)s1 * 128);

        for (int j = 0; j < cend; j += 16) {
            int jn = (j + 16 < cend) ? j + 16 : j;     // wave-uniform select
            int   sn0 = __shfl(me.x, jn + grp, 64);
            float wn0 = __shfl(mw,  jn + grp, 64);
            int   sn1 = __shfl(me.x, jn + 8 + grp, 64);
            float wn1 = __shfl(mw,  jn + 8 + grp, 64);
            uint4 rn0 = *(const uint4*)(Hfl + (size_t)sn0 * 128);  // issued before
            uint4 rn1 = *(const uint4*)(Hfl + (size_t)sn1 * 128);  // consuming r0/r1
            PKC(r0, w0);
            PKC(r1, w1);
            r0 = rn0; r1 = rn1; w0 = wn0; w1 = wn1;
        }
    }
    // reduce across the 8 edge-groups (pk adds)
    RED3(a0); RED3(a1); RED3(a2); RED3(a3);

    // self-loop + bias + relu (8 contiguous features per fl-lane, this half)
    float dd = dis[nd], sn = dd * dd;
    uint4 rs = *(const uint4*)(Hfl + (size_t)nd * 128);
    float4 bb0 = ((const float4*)bias)[half * 16 + fl * 2];
    float4 bb1 = ((const float4*)bias)[half * 16 + fl * 2 + 1];
    f32x2 s2; s2.x = sn; s2.y = sn;
    f32x2 bv;
    a0 = __builtin_elementwise_fma(up2(rs.x), s2, a0); bv.x = bb0.x; bv.y = bb0.y; a0 = a0 + bv;
    a1 = __builtin_elementwise_fma(up2(rs.y), s2, a1); bv.x = bb0.z; bv.y = bb0.w; a1 = a1 + bv;
    a2 = __builtin_elementwise_fma(up2(rs.z), s2, a2); bv.x = bb1.x; bv.y = bb1.y; a2 = a2 + bv;
    a3 = __builtin_elementwise_fma(up2(rs.w), s2, a3); bv.x = bb1.z; bv.y = bb1.w; a3 = a3 + bv;
    f32x2 zz = (f32x2){0.f, 0.f};
    a0 = __builtin_elementwise_max(a0, zz);
    a1 = __builtin_elementwise_max(a1, zz);
    a2 = __builtin_elementwise_max(a2, zz);
    a3 = __builtin_elementwise_max(a3, zz);

    if (node < n && grp == 0) {
        uint4 pk;
        asm("v_cvt_pk_bf16_f32 %0, %1, %2" : "=v"(pk.x) : "v"(a0.x), "v"(a0.y));
        asm("v_cvt_pk_bf16_f32 %0, %1, %2" : "=v"(pk.y) : "v"(a1.x), "v"(a1.y));
        asm("v_cvt_pk_bf16_f32 %0, %1, %2" : "=v"(pk.z) : "v"(a2.x), "v"(a2.y));
        asm("v_cvt_pk_bf16_f32 %0, %1, %2" : "=v"(pk.w) : "v"(a3.x), "v"(a3.y));
        *(uint4*)(outb + (size_t)node * 128 + half * 64 + fl * 8) = pk;
    }
}

// ---- JK head (MFMA): out = log_softmax((x1+x2) @ lw + lb) -----------------
// Block = 64 nodes, 4 waves x 16 rows. A = x1+x2 split hi/lo bf16 in LDS;
// B = lwt split hi/lo (48 padded cols). 3 MFMAs per (kt,nt) give
// hi*hi + hi*lo + lo*hi  (~2^-16 rel error). C layout: col = nt*16 + mrow,
// row = wave*16 + quad*4 + r. Row-softmax via in-quad shuffles (xor 1,2,4,8).
__global__ __launch_bounds__(256) void head_k(const unsigned short* __restrict__ x1b,
                                              const unsigned short* __restrict__ x2b,
                                              const unsigned short* __restrict__ lwt_hi,
                                              const unsigned short* __restrict__ lwt_lo,
                                              const float* __restrict__ lb,
                                              float* __restrict__ out, int n) {
    __shared__ unsigned short Ah[64][136];   // +8 pad: conflict-free b128 reads
    __shared__ unsigned short Al[64][136];
    __shared__ unsigned short Bh[48][136];
    __shared__ unsigned short Bl[48][136];
    const int tid = threadIdx.x;
    const int wave = tid >> 6, lane = tid & 63;
    const int quad = lane >> 4, mrow = lane & 15;
    const int base = blockIdx.x * 64;

    // stage A: JK sum, split into hi+lo bf16
    for (int i = tid; i < 1024; i += 256) {
        int row = i >> 4, oct = i & 15;
        int node = base + row; int nd = node < n ? node : n - 1;
        uint4 u1 = *(const uint4*)(x1b + (size_t)nd * 128 + oct * 8);
        uint4 u2 = *(const uint4*)(x2b + (size_t)nd * 128 + oct * 8);
        unsigned uu1[4] = {u1.x, u1.y, u1.z, u1.w};
        unsigned uu2[4] = {u2.x, u2.y, u2.z, u2.w};
        union { short8 v; unsigned short u[8]; } H, L;
#pragma unroll
        for (int q = 0; q < 4; q++) {
            float vl = bflo(uu1[q]) + bflo(uu2[q]);
            float vh = bfhi(uu1[q]) + bfhi(uu2[q]);
            unsigned short hl = f2bf(vl), hh = f2bf(vh);
            H.u[q * 2]     = hl;  L.u[q * 2]     = f2bf(vl - bf2f(hl));
            H.u[q * 2 + 1] = hh;  L.u[q * 2 + 1] = f2bf(vh - bf2f(hh));
        }
        *(short8*)&Ah[row][oct * 8] = H.v;
        *(short8*)&Al[row][oct * 8] = L.v;
    }
    // stage B: pre-split lw^T (48x128)
    for (int i = tid; i < 768; i += 256) {
        int row = i >> 4, oct = i & 15;
        *(short8*)&Bh[row][oct * 8] = *(const short8*)&lwt_hi[row * 128 + oct * 8];
        *(short8*)&Bl[row][oct * 8] = *(const short8*)&lwt_lo[row * 128 + oct * 8];
    }
    __syncthreads();

    f32x4 acc[3];
#pragma unroll
    for (int nt = 0; nt < 3; nt++) acc[nt] = (f32x4){0.f, 0.f, 0.f, 0.f};
#pragma unroll
    for (int kt = 0; kt < 128; kt += 32) {
        short8 ah = *(short8*)&Ah[wave * 16 + mrow][kt + quad * 8];
        short8 al = *(short8*)&Al[wave * 16 + mrow][kt + quad * 8];
#pragma unroll
        for (int nt = 0; nt < 3; nt++) {
            short8 bh = *(short8*)&Bh[nt * 16 + mrow][kt + quad * 8];
            short8 bl = *(short8*)&Bl[nt * 16 + mrow][kt + quad * 8];
            acc[nt] = __builtin_amdgcn_mfma_f32_16x16x32_bf16(ah, bh, acc[nt], 0, 0, 0);
            acc[nt] = __builtin_amdgcn_mfma_f32_16x16x32_bf16(ah, bl, acc[nt], 0, 0, 0);
            acc[nt] = __builtin_amdgcn_mfma_f32_16x16x32_bf16(al, bh, acc[nt], 0, 0, 0);
        }
    }

    // bias + row-wise log_softmax. cols: mrow, 16+mrow always valid (<41);
    // 32+mrow valid iff mrow<9.
    const bool v2ok = (mrow < 9);
    const float lb0 = lb[mrow];
    const float lb1 = lb[16 + mrow];
    const float lb2 = v2ok ? lb[32 + mrow] : 0.f;
#pragma unroll
    for (int r = 0; r < 4; r++) {
        int node = base + wave * 16 + quad * 4 + r;
        float v0 = acc[0][r] + lb0;
        float v1 = acc[1][r] + lb1;
        float v2 = v2ok ? acc[2][r] + lb2 : -INFINITY;
        float m = fmaxf(fmaxf(v0, v1), v2);
#pragma unroll
        for (int off = 1; off < 16; off <<= 1) m = fmaxf(m, __shfl_xor(m, off, 64));
        float e = expf(v0 - m) + expf(v1 - m) + (v2ok ? expf(v2 - m) : 0.f);
#pragma unroll
        for (int off = 1; off < 16; off <<= 1) e += __shfl_xor(e, off, 64);
        float lse = m + logf(e);
        if (node < n) {
            out[(size_t)node * 41 + mrow] = v0 - lse;
            out[(size_t)node * 41 + 16 + mrow] = v1 - lse;
            if (v2ok) out[(size_t)node * 41 + 32 + mrow] = v2 - lse;
        }
    }
}

extern "C" void kernel_launch(void* const* d_in, const int* in_sizes, int n_in,
                              void* d_out, int out_size, void* d_ws, size_t ws_size,
                              hipStream_t stream) {
    const float* x  = (const float*)d_in[0];
    const int*   ei = (const int*)d_in[1];
    const float* W1 = (const float*)d_in[2];
    const float* b1 = (const float*)d_in[3];
    const float* W2 = (const float*)d_in[4];
    const float* b2 = (const float*)d_in[5];
    const float* lw = (const float*)d_in[6];
    const float* lb = (const float*)d_in[7];
    float* out = (float*)d_out;

    const int n = in_sizes[0] / 256;   // 100000
    const int E = in_sizes[1] / 2;     // 1600000
    const int* src = ei;
    const int* dst = ei + E;

    // workspace layout (~99 MB)
    int*   cnt     = (int*)d_ws;                       // NPAD
    int*   offs    = cnt + NPAD;                       // NPAD
    int*   rank    = offs + NPAD;                      // Epad ints (6.4 MB)
    size_t Epad    = ((size_t)E + 255) & ~(size_t)255;
    int*   partial = rank + Epad;                      // 1024
    float* dis     = (float*)(partial + 1024);         // NPAD
    int2*  eadj    = (int2*)(dis + NPAD);              // Epad pairs (8 B)
    unsigned short* Wt1 = (unsigned short*)(eadj + Epad);  // 256*128 bf16
    unsigned short* Wt2 = Wt1 + 256 * 128;                 // 128*128 bf16
    unsigned short* Hb  = Wt2 + 128 * 128;                 // n*128 bf16
    unsigned short* X1b = Hb + (size_t)n * 128;            // n*128 bf16
    unsigned short* X2b = X1b + (size_t)n * 128;           // n*128 bf16
    unsigned short* Lh  = X2b + (size_t)n * 128;           // 48*128 bf16 (lw hi)
    unsigned short* Ll  = Lh + 48 * 128;                   // 48*128 bf16 (lw lo)

    const int nscan = (n + CHUNK - 1) / CHUNK;         // 98 (<=128)
    const int histB = (E + 255) / 256;                 // 6250
    const int wcastB = (256 * 128 + 128 * 128 + 48 * 128 + 255) / 256;  // 216
    const int gemmB = (n + 63) / 64;                   // 1563
    const int NB = (n + 3) / 4;                        // node-blocks (4/block)
    const int gathB = 8 * ((NB + 3) / 4);              // 8 XCD-combos

    hipMemsetAsync(cnt, 0, (size_t)n * sizeof(int), stream);

    // CSR hist (+rank) + weight prep (independent, one low-resource dispatch)
    mega1<<<histB + wcastB, 256, 0, stream>>>(dst, cnt, rank, E, histB, W1, Wt1, W2, Wt2,
                                              lw, Lh, Ll);
    scan_partial<<<nscan, 256, 0, stream>>>(cnt, partial, n);
    scan_final<<<nscan, 256, 0, stream>>>(cnt, partial, offs, dis, n, nscan);
    permute_all<<<histB, 256, 0, stream>>>(src, dst, rank, dis, offs, eadj, E);

    // layer 1: transform + aggregate (feature-split, XCD-pinned)
    gemm1_k<<<gemmB, 256, 0, stream>>>(x, Wt1, Hb, n);
    gather_h<<<gathB, 256, 0, stream>>>(Hb, eadj, offs, cnt, dis, b1, X1b, n);

    // layer 2 transform + aggregate
    gemm2_k<<<gemmB, 256, 0, stream>>>(X1b, Wt2, Hb, n);
    gather_h<<<gathB, 256, 0, stream>>>(Hb, eadj, offs, cnt, dis, b2, X2b, n);

    // JK + linear + log_softmax (MFMA, bf16x2 split)
    head_k<<<gemmB, 256, 0, stream>>>(X1b, X2b, Lh, Ll, lb, out, n);
}